// Round 2
// baseline (601.415 us; speedup 1.0000x reference)
//
#include <hip/hip_runtime.h>
#include <hip/hip_bf16.h>

// B=4, M=3, N=2048, DIM=512, H=4, HD=128, SCALE=sqrt(128). BM=12.
// ws (bf16): Q [BM][H][N][HD] | K [BM][H][N][HD] | Vt [BM][H][HD][N]

typedef short s16x8 __attribute__((ext_vector_type(8)));
typedef unsigned short u16x8 __attribute__((ext_vector_type(8)));
typedef float f32x4 __attribute__((ext_vector_type(4)));

#define MFMA16(a, b, c) __builtin_amdgcn_mfma_f32_16x16x32_bf16((a), (b), (c), 0, 0, 0)

static __device__ __forceinline__ unsigned short f2bf(float f) {
    union { float f; unsigned u; } v; v.f = f;
    unsigned r = v.u + 0x7FFFu + ((v.u >> 16) & 1u);   // RNE
    return (unsigned short)(r >> 16);
}
// HW packed f32->bf16 RNE: lo = a, hi = b. No builtin on gfx950 -> inline asm.
static __device__ __forceinline__ unsigned pk2(float a, float b) {
    unsigned r;
    asm("v_cvt_pk_bf16_f32 %0, %1, %2" : "=v"(r) : "v"(a), "v"(b));
    return r;
}

// ---------------------------------------------------------------------------
// Phase 1: QKV projection. 128x128 tile/block, 4 waves 2x2 of 64x64, BK=64.
// Round 2: 1.5-deep load pipeline. Previously loads for tile t+1 issued at
// iteration top but were consumed (convert+ds_write) right after ~300 cyc of
// MFMA -> exposed HBM latency each K-step. Now two named register sets (A=even
// tiles, B=odd tiles; static indexing, no runtime-indexed arrays): tile t+1 is
// written from regs loaded two MFMA-phases + a barrier earlier. +64 VGPR is
// free: kernel is LDS-capped at 2 blocks/CU (64KB), unified regs <= 256 ok.
// ---------------------------------------------------------------------------
#define OSTR 72

__global__ __launch_bounds__(256, 2)
void qkv_proj_kernel(const float* __restrict__ Xq, const float* __restrict__ Xk,
                     const float* __restrict__ Xv,
                     const float* __restrict__ Wq, const float* __restrict__ bq,
                     const float* __restrict__ Wk, const float* __restrict__ bk,
                     const float* __restrict__ Wv, const float* __restrict__ bv,
                     unsigned short* __restrict__ ws_q,
                     unsigned short* __restrict__ ws_k,
                     unsigned short* __restrict__ ws_vt)
{
    // byte layout: buf0 A [0,16K) B [16K,32K) | buf1 A [32K,48K) B [48K,64K)
    __shared__ __align__(16) char smem[65536];

    const int which = blockIdx.z;
    const float* X    = (which == 0) ? Xq : (which == 1) ? Xk : Xv;
    const float* W    = (which == 0) ? Wq : (which == 1) ? Wk : Wv;
    const float* bias = (which == 0) ? bq : (which == 1) ? bk : bv;

    const int r0 = blockIdx.x * 128;
    const int c0 = blockIdx.y * 128;
    const int tid = threadIdx.x;
    const int lane = tid & 63, wave = tid >> 6;
    const int l15 = lane & 15, quad = lane >> 4;
    const int wr = (wave >> 1) * 64, wc = (wave & 1) * 64;

    // staging roles: thread covers 16B granule scol of rows srow+16*i
    const int srow = tid >> 4;          // 0..15
    const int scol = tid & 15;          // 16B granule within 64-float k-slice
    const int cf = scol * 4;            // float col offset
    const int cb = scol * 8;            // byte col offset in 128B bf16 row

    f32x4 acc[4][4] = {};
    float4 raA[8], rbA[8], raB[8], rbB[8];

#define QKV_LOAD(RA, RB, T) { \
        const int kn_ = (T) * 64; \
        _Pragma("unroll") \
        for (int i = 0; i < 8; ++i) { \
            const int row_ = i * 16 + srow; \
            RA[i] = *(const float4*)&X[(size_t)(r0 + row_) * 512 + kn_ + cf]; \
            RB[i] = *(const float4*)&W[(size_t)(c0 + row_) * 512 + kn_ + cf]; \
        } }

#define QKV_WRITE(RA, RB, T) { \
        char* An_ = smem + ((T) & 1) * 32768; \
        char* Bn_ = An_ + 16384; \
        _Pragma("unroll") \
        for (int i = 0; i < 8; ++i) { \
            const int row_ = i * 16 + srow; \
            uint2 wa_, wb_; \
            wa_.x = pk2(RA[i].x, RA[i].y); wa_.y = pk2(RA[i].z, RA[i].w); \
            wb_.x = pk2(RB[i].x, RB[i].y); wb_.y = pk2(RB[i].z, RB[i].w); \
            const int sw_ = cb ^ ((row_ & 7) << 4); \
            *(uint2*)(An_ + row_ * 128 + sw_) = wa_; \
            *(uint2*)(Bn_ + row_ * 128 + sw_) = wb_; \
        } }

#define QKV_MFMA(PAR) { \
        char* Ac_ = smem + (PAR) * 32768; \
        char* Bc_ = Ac_ + 16384; \
        _Pragma("unroll") \
        for (int kk = 0; kk < 2; ++kk) { \
            s16x8 af_[4], bf_[4]; \
            _Pragma("unroll") \
            for (int mi = 0; mi < 4; ++mi) { \
                const int row_ = wr + mi * 16 + l15; \
                af_[mi] = *(const s16x8*)(Ac_ + row_ * 128 + \
                                          ((kk * 64 + quad * 16) ^ ((row_ & 7) << 4))); \
            } \
            _Pragma("unroll") \
            for (int ni = 0; ni < 4; ++ni) { \
                const int row_ = wc + ni * 16 + l15; \
                bf_[ni] = *(const s16x8*)(Bc_ + row_ * 128 + \
                                          ((kk * 64 + quad * 16) ^ ((row_ & 7) << 4))); \
            } \
            _Pragma("unroll") \
            for (int mi = 0; mi < 4; ++mi) \
                _Pragma("unroll") \
                for (int ni = 0; ni < 4; ++ni) \
                    acc[mi][ni] = MFMA16(af_[mi], bf_[ni], acc[mi][ni]); \
        } }

    // prologue: tile0 -> buf0 (latency exposed once), tile1 in flight in B
    QKV_LOAD(raA, rbA, 0);
    QKV_WRITE(raA, rbA, 0);
    QKV_LOAD(raB, rbB, 1);
    __syncthreads();

    for (int it2 = 0; it2 < 4; ++it2) {
        // even it = 2*it2: A free -> load tile 2*it2+2; MFMA buf0; write tile 2*it2+1 (B)
        if (it2 < 3) QKV_LOAD(raA, rbA, 2 * it2 + 2);
        QKV_MFMA(0);
        QKV_WRITE(raB, rbB, 2 * it2 + 1);
        __syncthreads();
        // odd it = 2*it2+1: B free -> load tile 2*it2+3; MFMA buf1; write tile 2*it2+2 (A)
        if (it2 < 3) QKV_LOAD(raB, rbB, 2 * it2 + 3);
        QKV_MFMA(1);
        if (it2 < 3) QKV_WRITE(raA, rbA, 2 * it2 + 2);
        __syncthreads();
    }

#undef QKV_LOAD
#undef QKV_WRITE
#undef QKV_MFMA

    float bvals[4];
    for (int ni = 0; ni < 4; ++ni) bvals[ni] = bias[c0 + wc + ni * 16 + l15];

    __syncthreads();
    unsigned short* St = (unsigned short*)smem + wave * (64 * OSTR);
    const int h = blockIdx.y;
    const int bm = (r0 + wr) >> 11;
    const int n0 = (r0 + wr) & 2047;

    if (which != 2) {
        for (int mi = 0; mi < 4; ++mi)
            for (int ni = 0; ni < 4; ++ni)
                for (int r = 0; r < 4; ++r)
                    St[(mi * 16 + quad * 4 + r) * OSTR + ni * 16 + l15] =
                        f2bf(acc[mi][ni][r] + bvals[ni]);
        unsigned short* dst = (which == 0) ? ws_q : ws_k;
        for (int p = 0; p < 8; ++p) {
            const int row = p * 8 + (lane >> 3);
            const int coff = (lane & 7) * 8;
            s16x8 v = *(const s16x8*)&St[row * OSTR + coff];
            *(s16x8*)&dst[((size_t)(bm * 4 + h) * 2048 + n0 + row) * 128 + wc + coff] = v;
        }
    } else {
        for (int mi = 0; mi < 4; ++mi)
            for (int ni = 0; ni < 4; ++ni)
                for (int r = 0; r < 4; ++r)
                    St[(ni * 16 + l15) * OSTR + mi * 16 + quad * 4 + r] =
                        f2bf(acc[mi][ni][r] + bvals[ni]);
        for (int p = 0; p < 8; ++p) {
            const int col = p * 8 + (lane >> 3);
            const int roff = (lane & 7) * 8;
            s16x8 v = *(const s16x8*)&St[col * OSTR + roff];
            *(s16x8*)&ws_vt[(((size_t)(bm * 4 + h)) * 128 + wc + col) * 2048 + n0 + roff] = v;
        }
    }
}

// ---------------------------------------------------------------------------
// Phase 2: flash attention, transposed form + LDS-staged K/V double buffer.
//   Round 2: staged K/V register->LDS writes moved from post-QK to post-PV.
//   Nothing reads Kn/Vn until after the barrier, so the write only has to
//   precede __syncthreads(); placing it last gives the global loads the whole
//   iteration (~2000+ cyc) to land instead of ~200 cyc of QK -> the per-it
//   s_waitcnt vmcnt stall (~500-900 cyc, the dominant stall in a kernel where
//   no pipe exceeds ~31% util) disappears. Zero register cost.
// ---------------------------------------------------------------------------
#define KSTR 272   // K' row stride bytes (32 rows x 256B data + 16 pad)
#define VSTR 80    // V' row stride bytes (128 rows x 64B data + 16 pad)
#define PQST 80    // P  row stride bytes (32 q x 64B data + 16 pad)
// LDS: K0[8704] K1[8704] V0[10240] V1[10240] P[4*2560] = 48128 B

__global__ __launch_bounds__(256)
void attn_kernel(const unsigned short* __restrict__ Qw,
                 const unsigned short* __restrict__ Kw,
                 const unsigned short* __restrict__ Vtw,
                 float* __restrict__ out)
{
    __shared__ char lds[48128];
    char* Kb0 = lds;
    char* Kb1 = lds + 8704;
    char* Vb0 = lds + 17408;
    char* Vb1 = lds + 27648;
    char* Pb  = lds + 37888;

    const int tid = threadIdx.x, lane = tid & 63, wave = tid >> 6;
    const int l15 = lane & 15, quad = lane >> 4;
    const int q0 = blockIdx.x * 128, h = blockIdx.y, bm = blockIdx.z;

    const unsigned short* Qh = Qw  + (size_t)(bm * 4 + h) * 2048 * 128;
    const unsigned short* Kh = Kw  + (size_t)(bm * 4 + h) * 2048 * 128;
    const unsigned short* Vh = Vtw + (size_t)(bm * 4 + h) * 128 * 2048;

    // staging roles (all 256 threads): K tile 32key x 128hd, V tile 128hd x 32n
    const int sk_key  = tid >> 3, sk_c   = tid & 7;   // 2x16B chunks of a 256B K row
    const int sv_hd   = tid >> 1, sv_hlf = tid & 1;   // 2x16B chunks of a 64B V row

    // qf: B-operand frags, 2 q-halves (qrow = q0 + wave*32 + qh*16 + l15)
    s16x8 qf[2][4];
    for (int qh = 0; qh < 2; ++qh)
        for (int kk = 0; kk < 4; ++kk)
            qf[qh][kk] = *(const s16x8*)&Qh[(size_t)(q0 + wave * 32 + qh * 16 + l15) * 128 + kk * 32 + quad * 8];

    // prologue: stage tile 0
    {
        u16x8 ka = *(const u16x8*)&Kh[(size_t)sk_key * 128 + sk_c * 16];
        u16x8 kb = *(const u16x8*)&Kh[(size_t)sk_key * 128 + sk_c * 16 + 8];
        u16x8 va = *(const u16x8*)&Vh[(size_t)sv_hd * 2048 + sv_hlf * 16];
        u16x8 vb = *(const u16x8*)&Vh[(size_t)sv_hd * 2048 + sv_hlf * 16 + 8];
        *(u16x8*)(Kb0 + sk_key * KSTR + sk_c * 32)      = ka;
        *(u16x8*)(Kb0 + sk_key * KSTR + sk_c * 32 + 16) = kb;
        *(u16x8*)(Vb0 + sv_hd * VSTR + sv_hlf * 32)      = va;
        *(u16x8*)(Vb0 + sv_hd * VSTR + sv_hlf * 32 + 16) = vb;
    }
    __syncthreads();

    f32x4 acc[2][8] = {};          // O^T: hd = mb*16+quad*4+r, qrow col = l15
    float rsum[2] = {0.f, 0.f};
    char* Pw = Pb + wave * 2560;   // wave-private P: [32 q][80 B]

    const float CEXP = 1.4426950408889634f / 11.313708498984761f;  // log2(e)/sqrt(128)

    for (int it = 0; it < 64; ++it) {
        const int k0 = it * 32;
        char* Kc = (it & 1) ? Kb1 : Kb0;
        char* Vc = (it & 1) ? Vb1 : Vb0;
        char* Kn = (it & 1) ? Kb0 : Kb1;
        char* Vn = (it & 1) ? Vb0 : Vb1;
        const bool do_stage = (it < 63);

        // issue next-tile global loads at the very top: they now have the
        // entire iteration (QK + softmax + PV) before the ds_write consumes them
        u16x8 ka, kb, va, vb;
        if (do_stage) {
            const int kn0 = k0 + 32;
            ka = *(const u16x8*)&Kh[(size_t)(kn0 + sk_key) * 128 + sk_c * 16];
            kb = *(const u16x8*)&Kh[(size_t)(kn0 + sk_key) * 128 + sk_c * 16 + 8];
            va = *(const u16x8*)&Vh[(size_t)sv_hd * 2048 + kn0 + sv_hlf * 16];
            vb = *(const u16x8*)&Vh[(size_t)sv_hd * 2048 + kn0 + sv_hlf * 16 + 8];
        }

        // ---- S^T = K Q^T on current K buffer ----
        f32x4 s[2][2] = {};
        __builtin_amdgcn_s_setprio(1);
        for (int kk = 0; kk < 4; ++kk) {
            s16x8 kf0 = *(const s16x8*)(Kc + (l15)      * KSTR + (kk * 4 + quad) * 16);
            s16x8 kf1 = *(const s16x8*)(Kc + (16 + l15) * KSTR + (kk * 4 + quad) * 16);
            s[0][0] = MFMA16(kf0, qf[0][kk], s[0][0]);
            s[0][1] = MFMA16(kf1, qf[0][kk], s[0][1]);
            s[1][0] = MFMA16(kf0, qf[1][kk], s[1][0]);
            s[1][1] = MFMA16(kf1, qf[1][kk], s[1][1]);
        }
        __builtin_amdgcn_s_setprio(0);

        // ---- P = exp(S/scale), pack bf16 pairs (HW cvt_pk), b64 writes ----
        for (int qh = 0; qh < 2; ++qh)
            for (int ni = 0; ni < 2; ++ni) {
                const float p0 = exp2f(s[qh][ni][0] * CEXP);
                const float p1 = exp2f(s[qh][ni][1] * CEXP);
                const float p2 = exp2f(s[qh][ni][2] * CEXP);
                const float p3 = exp2f(s[qh][ni][3] * CEXP);
                rsum[qh] += (p0 + p1) + (p2 + p3);
                uint2 w; w.x = pk2(p0, p1); w.y = pk2(p2, p3);
                *(uint2*)(Pw + (qh * 16 + l15) * PQST + ni * 32 + quad * 8) = w;
            }

        // ---- O^T += Vt P^T on current V buffer (K-dim = 32, one MFMA step) ----
        s16x8 pf0 = *(const s16x8*)(Pw + (l15)      * PQST + quad * 16);
        s16x8 pf1 = *(const s16x8*)(Pw + (16 + l15) * PQST + quad * 16);
        __builtin_amdgcn_s_setprio(1);
        for (int mb = 0; mb < 8; ++mb) {
            s16x8 vtf = *(const s16x8*)(Vc + (mb * 16 + l15) * VSTR + quad * 16);
            acc[0][mb] = MFMA16(vtf, pf0, acc[0][mb]);
            acc[1][mb] = MFMA16(vtf, pf1, acc[1][mb]);
        }
        __builtin_amdgcn_s_setprio(0);

        // ---- write staged next tile to LDS (moved post-PV: loads fully landed,
        //      nothing reads Kn/Vn until after the barrier) ----
        if (do_stage) {
            *(u16x8*)(Kn + sk_key * KSTR + sk_c * 32)      = ka;
            *(u16x8*)(Kn + sk_key * KSTR + sk_c * 32 + 16) = kb;
            *(u16x8*)(Vn + sv_hd * VSTR + sv_hlf * 32)      = va;
            *(u16x8*)(Vn + sv_hd * VSTR + sv_hlf * 32 + 16) = vb;
        }

        __syncthreads();   // staged buffer complete + current buffer reads done
    }

    // ---- epilogue: reduce rsum over quads, scale, direct float4 stores ----
    for (int qh = 0; qh < 2; ++qh) {
        rsum[qh] += __shfl_xor(rsum[qh], 16);
        rsum[qh] += __shfl_xor(rsum[qh], 32);
    }
    for (int qh = 0; qh < 2; ++qh) {
        const float inv = 1.f / rsum[qh];
        float* orow = out + ((size_t)bm * 2048 + q0 + wave * 32 + qh * 16 + l15) * 512 + h * 128;
        for (int mb = 0; mb < 8; ++mb) {
            float4 v;
            v.x = acc[qh][mb][0] * inv; v.y = acc[qh][mb][1] * inv;
            v.z = acc[qh][mb][2] * inv; v.w = acc[qh][mb][3] * inv;
            *(float4*)&orow[mb * 16 + quad * 4] = v;
        }
    }
}

extern "C" void kernel_launch(void* const* d_in, const int* in_sizes, int n_in,
                              void* d_out, int out_size, void* d_ws, size_t ws_size,
                              hipStream_t stream) {
    const float* Xq = (const float*)d_in[0];
    const float* Xk = (const float*)d_in[1];
    const float* Xv = (const float*)d_in[2];
    const float* Wq = (const float*)d_in[3];
    const float* bq = (const float*)d_in[4];
    const float* Wk = (const float*)d_in[5];
    const float* bk = (const float*)d_in[6];
    const float* Wv = (const float*)d_in[7];
    const float* bv = (const float*)d_in[8];
    float* out = (float*)d_out;

    unsigned short* ws = (unsigned short*)d_ws;
    const size_t per_tensor = (size_t)12 * 4 * 2048 * 128;
    unsigned short* ws_q  = ws;
    unsigned short* ws_k  = ws + per_tensor;
    unsigned short* ws_vt = ws + 2 * per_tensor;

    qkv_proj_kernel<<<dim3(192, 4, 3), 256, 0, stream>>>(
        Xq, Xk, Xv, Wq, bq, Wk, bk, Wv, bv, ws_q, ws_k, ws_vt);

    attn_kernel<<<dim3(16, 4, 12), 256, 0, stream>>>(ws_q, ws_k, ws_vt, out);
}

// Round 3
// 421.209 us; speedup vs baseline: 1.4278x; 1.4278x over previous
//
#include <hip/hip_runtime.h>
#include <hip/hip_bf16.h>

// B=4, M=3, N=2048, DIM=512, H=4, HD=128, SCALE=sqrt(128). BM=12.
// ws (bf16): Q [BM][H][N][HD] | K [BM][H][N][HD] | Vt [BM][H][HD][N]

typedef short s16x8 __attribute__((ext_vector_type(8)));
typedef unsigned short u16x8 __attribute__((ext_vector_type(8)));
typedef float f32x4 __attribute__((ext_vector_type(4)));

#define MFMA16(a, b, c) __builtin_amdgcn_mfma_f32_16x16x32_bf16((a), (b), (c), 0, 0, 0)

static __device__ __forceinline__ unsigned short f2bf(float f) {
    union { float f; unsigned u; } v; v.f = f;
    unsigned r = v.u + 0x7FFFu + ((v.u >> 16) & 1u);   // RNE
    return (unsigned short)(r >> 16);
}
// HW packed f32->bf16 RNE: lo = a, hi = b. No builtin on gfx950 -> inline asm.
static __device__ __forceinline__ unsigned pk2(float a, float b) {
    unsigned r;
    asm("v_cvt_pk_bf16_f32 %0, %1, %2" : "=v"(r) : "v"(a), "v"(b));
    return r;
}
// raw v_exp_f32 (2^x); args bounded ~[-2,2] here, no denorm/overflow concerns
static __device__ __forceinline__ float exp2_hw(float x) {
    float r;
    asm("v_exp_f32 %0, %1" : "=v"(r) : "v"(x));
    return r;
}

// ---------------------------------------------------------------------------
// Phase 1: QKV projection. 128x128 tile/block, 4 waves 2x2 of 64x64, BK=64.
// Round-1 structure restored verbatim: single prefetch register set (ra/rb),
// double-buffered XOR-swizzled LDS, cvt_pk packed conversion. The Round-2
// 1.5-deep variant (4 register sets) spilled to scratch (WRITE_SIZE 441MB,
// 311us) -- +64 VGPR was NOT free. Do not re-add without checking numRegs.
// ---------------------------------------------------------------------------
#define OSTR 72

__global__ __launch_bounds__(256, 2)
void qkv_proj_kernel(const float* __restrict__ Xq, const float* __restrict__ Xk,
                     const float* __restrict__ Xv,
                     const float* __restrict__ Wq, const float* __restrict__ bq,
                     const float* __restrict__ Wk, const float* __restrict__ bk,
                     const float* __restrict__ Wv, const float* __restrict__ bv,
                     unsigned short* __restrict__ ws_q,
                     unsigned short* __restrict__ ws_k,
                     unsigned short* __restrict__ ws_vt)
{
    // byte layout: buf0 A [0,16K) B [16K,32K) | buf1 A [32K,48K) B [48K,64K)
    __shared__ __align__(16) char smem[65536];

    const int which = blockIdx.z;
    const float* X    = (which == 0) ? Xq : (which == 1) ? Xk : Xv;
    const float* W    = (which == 0) ? Wq : (which == 1) ? Wk : Wv;
    const float* bias = (which == 0) ? bq : (which == 1) ? bk : bv;

    const int r0 = blockIdx.x * 128;
    const int c0 = blockIdx.y * 128;
    const int tid = threadIdx.x;
    const int lane = tid & 63, wave = tid >> 6;
    const int l15 = lane & 15, quad = lane >> 4;
    const int wr = (wave >> 1) * 64, wc = (wave & 1) * 64;

    // staging roles: thread covers 16B granule scol of rows srow+16*i
    const int srow = tid >> 4;          // 0..15
    const int scol = tid & 15;          // 16B granule within 64-float k-slice
    const int cf = scol * 4;            // float col offset
    const int cb = scol * 8;            // byte col offset in 128B bf16 row

    f32x4 acc[4][4] = {};

    // prologue: stage k0=0 into buf0
    {
        char* A0 = smem;
        char* B0 = smem + 16384;
        for (int i = 0; i < 8; ++i) {
            const int row = i * 16 + srow;
            float4 fa = *(const float4*)&X[(size_t)(r0 + row) * 512 + cf];
            float4 fb = *(const float4*)&W[(size_t)(c0 + row) * 512 + cf];
            uint2 wa, wb;
            wa.x = pk2(fa.x, fa.y); wa.y = pk2(fa.z, fa.w);
            wb.x = pk2(fb.x, fb.y); wb.y = pk2(fb.z, fb.w);
            const int sw = cb ^ ((row & 7) << 4);
            *(uint2*)(A0 + row * 128 + sw) = wa;
            *(uint2*)(B0 + row * 128 + sw) = wb;
        }
    }
    __syncthreads();

    for (int it = 0; it < 8; ++it) {
        char* Ac = smem + (it & 1) * 32768;
        char* Bc = Ac + 16384;
        const bool pre = (it < 7);

        // issue next K-step's global loads early (land during MFMA below)
        float4 ra[8], rb[8];
        if (pre) {
            const int kn = (it + 1) * 64;
            for (int i = 0; i < 8; ++i) {
                const int row = i * 16 + srow;
                ra[i] = *(const float4*)&X[(size_t)(r0 + row) * 512 + kn + cf];
                rb[i] = *(const float4*)&W[(size_t)(c0 + row) * 512 + kn + cf];
            }
        }

        // MFMA on current buffer
        for (int kk = 0; kk < 2; ++kk) {
            s16x8 af[4], bf_[4];
            for (int mi = 0; mi < 4; ++mi) {
                const int row = wr + mi * 16 + l15;
                af[mi] = *(const s16x8*)(Ac + row * 128 +
                                         ((kk * 64 + quad * 16) ^ ((row & 7) << 4)));
            }
            for (int ni = 0; ni < 4; ++ni) {
                const int row = wc + ni * 16 + l15;
                bf_[ni] = *(const s16x8*)(Bc + row * 128 +
                                          ((kk * 64 + quad * 16) ^ ((row & 7) << 4)));
            }
            for (int mi = 0; mi < 4; ++mi)
                for (int ni = 0; ni < 4; ++ni)
                    acc[mi][ni] = MFMA16(af[mi], bf_[ni], acc[mi][ni]);
        }

        // convert + write prefetched tile to the other buffer
        if (pre) {
            char* An = smem + ((it & 1) ^ 1) * 32768;
            char* Bn = An + 16384;
            for (int i = 0; i < 8; ++i) {
                const int row = i * 16 + srow;
                uint2 wa, wb;
                wa.x = pk2(ra[i].x, ra[i].y); wa.y = pk2(ra[i].z, ra[i].w);
                wb.x = pk2(rb[i].x, rb[i].y); wb.y = pk2(rb[i].z, rb[i].w);
                const int sw = cb ^ ((row & 7) << 4);
                *(uint2*)(An + row * 128 + sw) = wa;
                *(uint2*)(Bn + row * 128 + sw) = wb;
            }
        }
        __syncthreads();
    }

    float bvals[4];
    for (int ni = 0; ni < 4; ++ni) bvals[ni] = bias[c0 + wc + ni * 16 + l15];

    __syncthreads();
    unsigned short* St = (unsigned short*)smem + wave * (64 * OSTR);
    const int h = blockIdx.y;
    const int bm = (r0 + wr) >> 11;
    const int n0 = (r0 + wr) & 2047;

    if (which != 2) {
        for (int mi = 0; mi < 4; ++mi)
            for (int ni = 0; ni < 4; ++ni)
                for (int r = 0; r < 4; ++r)
                    St[(mi * 16 + quad * 4 + r) * OSTR + ni * 16 + l15] =
                        f2bf(acc[mi][ni][r] + bvals[ni]);
        unsigned short* dst = (which == 0) ? ws_q : ws_k;
        for (int p = 0; p < 8; ++p) {
            const int row = p * 8 + (lane >> 3);
            const int coff = (lane & 7) * 8;
            s16x8 v = *(const s16x8*)&St[row * OSTR + coff];
            *(s16x8*)&dst[((size_t)(bm * 4 + h) * 2048 + n0 + row) * 128 + wc + coff] = v;
        }
    } else {
        for (int mi = 0; mi < 4; ++mi)
            for (int ni = 0; ni < 4; ++ni)
                for (int r = 0; r < 4; ++r)
                    St[(ni * 16 + l15) * OSTR + mi * 16 + quad * 4 + r] =
                        f2bf(acc[mi][ni][r] + bvals[ni]);
        for (int p = 0; p < 8; ++p) {
            const int col = p * 8 + (lane >> 3);
            const int roff = (lane & 7) * 8;
            s16x8 v = *(const s16x8*)&St[col * OSTR + roff];
            *(s16x8*)&ws_vt[(((size_t)(bm * 4 + h)) * 128 + wc + col) * 2048 + n0 + roff] = v;
        }
    }
}

// ---------------------------------------------------------------------------
// Phase 2: flash attention. Round 3 changes:
//  (a) K LDS: linear 256B rows + 16B-granule XOR swizzle g^=(row&7), BOTH
//      write and read sides (reg-staged, rule #21). Old KSTR=272 staging
//      write was an 8-way bank conflict (bank = 4k+8c mod 32 -> 8 banks/64
//      lanes) = bulk of the 23.6M SQ_LDS_BANK_CONFLICT cycles. Swizzled
//      pattern lands exactly 8 words/bank on both sides = conflict-free.
//  (b) P LDS round-trip replaced by in-register quad-exchange via
//      v_permlane32_swap + v_permlane16_swap (gfx950). The S->pf transform
//      is a pure quad permutation at fixed l15: per qh,
//      swap32(x0,x1); swap16(x0,x1) -> pf words {0,2}; same for y -> {1,3}.
//      Removes 6 LDS ops + ds_write->ds_read latency per wave-iter and the
//      10.2KB P buffer (LDS 48128 -> 36864).
//  (c) exp2f -> raw v_exp_f32 (args in ~[-2,2]).
// ---------------------------------------------------------------------------
#define VSTR 80    // V' row stride bytes (128 rows x 64B data + 16 pad)
// LDS: K0[8192] K1[8192] V0[10240] V1[10240] = 36864 B

__global__ __launch_bounds__(256)
void attn_kernel(const unsigned short* __restrict__ Qw,
                 const unsigned short* __restrict__ Kw,
                 const unsigned short* __restrict__ Vtw,
                 float* __restrict__ out)
{
    __shared__ char lds[36864];
    char* Kb0 = lds;
    char* Kb1 = lds + 8192;
    char* Vb0 = lds + 16384;
    char* Vb1 = lds + 26624;

    const int tid = threadIdx.x, lane = tid & 63, wave = tid >> 6;
    const int l15 = lane & 15, quad = lane >> 4;
    const int q0 = blockIdx.x * 128, h = blockIdx.y, bm = blockIdx.z;

    const unsigned short* Qh = Qw  + (size_t)(bm * 4 + h) * 2048 * 128;
    const unsigned short* Kh = Kw  + (size_t)(bm * 4 + h) * 2048 * 128;
    const unsigned short* Vh = Vtw + (size_t)(bm * 4 + h) * 128 * 2048;

    // staging roles (all 256 threads): K tile 32key x 128hd, V tile 128hd x 32n
    const int sk_key  = tid >> 3, sk_c   = tid & 7;   // 2x16B granules of a 256B K row
    const int sv_hd   = tid >> 1, sv_hlf = tid & 1;   // 2x16B chunks of a 64B V row
    const int skx = sk_key & 7;                       // K write-side granule xor
    const int krx = (l15 & 7) << 4;                   // K read-side byte xor

    // qf: B-operand frags, 2 q-halves (qrow = q0 + wave*32 + qh*16 + l15)
    s16x8 qf[2][4];
    for (int qh = 0; qh < 2; ++qh)
        for (int kk = 0; kk < 4; ++kk)
            qf[qh][kk] = *(const s16x8*)&Qh[(size_t)(q0 + wave * 32 + qh * 16 + l15) * 128 + kk * 32 + quad * 8];

    // prologue: stage tile 0
    {
        u16x8 ka = *(const u16x8*)&Kh[(size_t)sk_key * 128 + sk_c * 16];
        u16x8 kb = *(const u16x8*)&Kh[(size_t)sk_key * 128 + sk_c * 16 + 8];
        u16x8 va = *(const u16x8*)&Vh[(size_t)sv_hd * 2048 + sv_hlf * 16];
        u16x8 vb = *(const u16x8*)&Vh[(size_t)sv_hd * 2048 + sv_hlf * 16 + 8];
        *(u16x8*)(Kb0 + sk_key * 256 + (((sk_c * 2) ^ skx) << 4))     = ka;
        *(u16x8*)(Kb0 + sk_key * 256 + (((sk_c * 2 + 1) ^ skx) << 4)) = kb;
        *(u16x8*)(Vb0 + sv_hd * VSTR + sv_hlf * 32)      = va;
        *(u16x8*)(Vb0 + sv_hd * VSTR + sv_hlf * 32 + 16) = vb;
    }
    __syncthreads();

    f32x4 acc[2][8] = {};          // O^T: hd = mb*16+quad*4+r, qrow col = l15
    float rsum[2] = {0.f, 0.f};

    const float CEXP = 1.4426950408889634f / 11.313708498984761f;  // log2(e)/sqrt(128)

    for (int it = 0; it < 64; ++it) {
        const int k0 = it * 32;
        char* Kc = (it & 1) ? Kb1 : Kb0;
        char* Vc = (it & 1) ? Vb1 : Vb0;
        char* Kn = (it & 1) ? Kb0 : Kb1;
        char* Vn = (it & 1) ? Vb0 : Vb1;
        const bool do_stage = (it < 63);

        // issue next-tile global loads at iteration top (whole iter to land)
        u16x8 ka, kb, va, vb;
        if (do_stage) {
            const int kn0 = k0 + 32;
            ka = *(const u16x8*)&Kh[(size_t)(kn0 + sk_key) * 128 + sk_c * 16];
            kb = *(const u16x8*)&Kh[(size_t)(kn0 + sk_key) * 128 + sk_c * 16 + 8];
            va = *(const u16x8*)&Vh[(size_t)sv_hd * 2048 + kn0 + sv_hlf * 16];
            vb = *(const u16x8*)&Vh[(size_t)sv_hd * 2048 + kn0 + sv_hlf * 16 + 8];
        }

        // ---- S^T = K Q^T on current K buffer (swizzled granule reads) ----
        f32x4 s[2][2] = {};
        __builtin_amdgcn_s_setprio(1);
        for (int kk = 0; kk < 4; ++kk) {
            s16x8 kf0 = *(const s16x8*)(Kc + l15 * 256        + (((kk * 4 + quad) << 4) ^ krx));
            s16x8 kf1 = *(const s16x8*)(Kc + (16 + l15) * 256 + (((kk * 4 + quad) << 4) ^ krx));
            s[0][0] = MFMA16(kf0, qf[0][kk], s[0][0]);
            s[0][1] = MFMA16(kf1, qf[0][kk], s[0][1]);
            s[1][0] = MFMA16(kf0, qf[1][kk], s[1][0]);
            s[1][1] = MFMA16(kf1, qf[1][kk], s[1][1]);
        }
        __builtin_amdgcn_s_setprio(0);

        // ---- P = exp2(S*CEXP); in-register quad exchange -> pf frags ----
        // lane (l15, q^) holds keys {4q^..4q^+3} (ni=0) and {16+4q^..} (ni=1)
        // for q-row qh*16+l15. Target: lane (l15, qt) needs keys 8qt..8qt+7.
        // swap32 then swap16 on (x0,x1) yields pf words 0 and 2; (y0,y1) -> 1,3.
        s16x8 pf[2];
        for (int qh = 0; qh < 2; ++qh) {
            const float p00 = exp2_hw(s[qh][0][0] * CEXP);
            const float p01 = exp2_hw(s[qh][0][1] * CEXP);
            const float p02 = exp2_hw(s[qh][0][2] * CEXP);
            const float p03 = exp2_hw(s[qh][0][3] * CEXP);
            const float p10 = exp2_hw(s[qh][1][0] * CEXP);
            const float p11 = exp2_hw(s[qh][1][1] * CEXP);
            const float p12 = exp2_hw(s[qh][1][2] * CEXP);
            const float p13 = exp2_hw(s[qh][1][3] * CEXP);
            rsum[qh] += ((p00 + p01) + (p02 + p03)) + ((p10 + p11) + (p12 + p13));
            unsigned x0 = pk2(p00, p01), y0 = pk2(p02, p03);
            unsigned x1 = pk2(p10, p11), y1 = pk2(p12, p13);
            asm("v_permlane32_swap_b32 %0, %1" : "+v"(x0), "+v"(x1));
            asm("v_permlane16_swap_b32 %0, %1" : "+v"(x0), "+v"(x1));
            asm("v_permlane32_swap_b32 %0, %1" : "+v"(y0), "+v"(y1));
            asm("v_permlane16_swap_b32 %0, %1" : "+v"(y0), "+v"(y1));
            union { unsigned u[4]; s16x8 v; } pu;
            pu.u[0] = x0; pu.u[1] = y0; pu.u[2] = x1; pu.u[3] = y1;
            pf[qh] = pu.v;
        }

        // ---- O^T += Vt P^T on current V buffer (K-dim = 32, one MFMA step) ----
        __builtin_amdgcn_s_setprio(1);
        for (int mb = 0; mb < 8; ++mb) {
            s16x8 vtf = *(const s16x8*)(Vc + (mb * 16 + l15) * VSTR + quad * 16);
            acc[0][mb] = MFMA16(vtf, pf[0], acc[0][mb]);
            acc[1][mb] = MFMA16(vtf, pf[1], acc[1][mb]);
        }
        __builtin_amdgcn_s_setprio(0);

        // ---- write staged next tile to LDS (post-PV: loads fully landed) ----
        if (do_stage) {
            *(u16x8*)(Kn + sk_key * 256 + (((sk_c * 2) ^ skx) << 4))     = ka;
            *(u16x8*)(Kn + sk_key * 256 + (((sk_c * 2 + 1) ^ skx) << 4)) = kb;
            *(u16x8*)(Vn + sv_hd * VSTR + sv_hlf * 32)      = va;
            *(u16x8*)(Vn + sv_hd * VSTR + sv_hlf * 32 + 16) = vb;
        }

        __syncthreads();   // staged buffer complete + current buffer reads done
    }

    // ---- epilogue: reduce rsum over quads, scale, direct float4 stores ----
    for (int qh = 0; qh < 2; ++qh) {
        rsum[qh] += __shfl_xor(rsum[qh], 16);
        rsum[qh] += __shfl_xor(rsum[qh], 32);
    }
    for (int qh = 0; qh < 2; ++qh) {
        const float inv = 1.f / rsum[qh];
        float* orow = out + ((size_t)bm * 2048 + q0 + wave * 32 + qh * 16 + l15) * 512 + h * 128;
        for (int mb = 0; mb < 8; ++mb) {
            float4 v;
            v.x = acc[qh][mb][0] * inv; v.y = acc[qh][mb][1] * inv;
            v.z = acc[qh][mb][2] * inv; v.w = acc[qh][mb][3] * inv;
            *(float4*)&orow[mb * 16 + quad * 4] = v;
        }
    }
}

extern "C" void kernel_launch(void* const* d_in, const int* in_sizes, int n_in,
                              void* d_out, int out_size, void* d_ws, size_t ws_size,
                              hipStream_t stream) {
    const float* Xq = (const float*)d_in[0];
    const float* Xk = (const float*)d_in[1];
    const float* Xv = (const float*)d_in[2];
    const float* Wq = (const float*)d_in[3];
    const float* bq = (const float*)d_in[4];
    const float* Wk = (const float*)d_in[5];
    const float* bk = (const float*)d_in[6];
    const float* Wv = (const float*)d_in[7];
    const float* bv = (const float*)d_in[8];
    float* out = (float*)d_out;

    unsigned short* ws = (unsigned short*)d_ws;
    const size_t per_tensor = (size_t)12 * 4 * 2048 * 128;
    unsigned short* ws_q  = ws;
    unsigned short* ws_k  = ws + per_tensor;
    unsigned short* ws_vt = ws + 2 * per_tensor;

    qkv_proj_kernel<<<dim3(192, 4, 3), 256, 0, stream>>>(
        Xq, Xk, Xv, Wq, bq, Wk, bk, Wv, bv, ws_q, ws_k, ws_vt);

    attn_kernel<<<dim3(16, 4, 12), 256, 0, stream>>>(ws_q, ws_k, ws_vt, out);
}